// Round 11
// baseline (1979.925 us; speedup 1.0000x reference)
//
#include <hip/hip_runtime.h>
#include <hip/hip_bf16.h>
#include <stdint.h>

#define NSTEP 126
#define NEVAL 504

typedef __bf16 v8bf __attribute__((ext_vector_type(8)));
typedef float  v4f  __attribute__((ext_vector_type(4)));

__device__ __forceinline__ unsigned short f2bf(float x) {
  union { float f; uint32_t u; } v; v.f = x;
  uint32_t u = v.u;
  uint32_t r = (u + 0x7FFFu + ((u >> 16) & 1u)) >> 16;
  return (unsigned short)r;
}
__device__ __forceinline__ float bf2f(unsigned short b) {
  union { uint32_t u; float f; } v; v.u = ((uint32_t)b) << 16;
  return v.f;
}

// ---------------- dtype detection ----------------
__global__ void k_detect(const uint32_t* __restrict__ xw, int* flag) {
  __shared__ int cnt;
  if (threadIdx.x == 0) cnt = 0;
  __syncthreads();
  uint32_t w = xw[threadIdx.x];
  int e = (int)((w >> 7) & 0xFF);
  int good = ((e >= 100) && (e <= 144)) || ((w & 0xFFFFu) == 0u);
  atomicAdd(&cnt, good);
  __syncthreads();
  if (threadIdx.x == 0) *flag = (cnt >= 192) ? 1 : 0;
}

// ---------------- input conversion ----------------
#define NCVT 15
struct CvtArgs {
  const void* src[NCVT];
  int dstoff[NCVT];
  int len[NCVT];
  int kind[NCVT];   // 1 = transpose initial_w; 2 = conv2 weight relayout
  int total;
};
__global__ void k_convert(CvtArgs a, float* __restrict__ ws, const int* __restrict__ flag) {
  int f = *flag;
  for (int i = blockIdx.x*256 + threadIdx.x; i < a.total; i += gridDim.x*256) {
    int t = 0; int rem = i;
    while (rem >= a.len[t]) { rem -= a.len[t]; t++; }
    float v = f ? bf2f(((const unsigned short*)a.src[t])[rem])
                : ((const float*)a.src[t])[rem];
    int d;
    if (a.kind[t] == 1) { int h = rem >> 9, c = rem & 511; d = a.dstoff[t] + c*64 + h; }
    else if (a.kind[t] == 2) {
      int co = rem / 288, r2 = rem % 288;
      int ci = r2 / 9, tt = r2 % 9;
      d = a.dstoff[t] + (co >> 4)*4608 + (ci*16 + (co & 15))*9 + tt;
    }
    else d = a.dstoff[t] + rem;
    ws[d] = v;
  }
}

__global__ void k_wbf16(const void* __restrict__ w2src, const void* __restrict__ w1src,
                        unsigned short* __restrict__ w2bf, unsigned short* __restrict__ w1bf,
                        const int* __restrict__ flag) {
  int f = *flag;
  const long N2 = 4194304, N1 = 8192;
  for (long i = (long)blockIdx.x*256 + threadIdx.x; i < N2 + N1; i += (long)gridDim.x*256) {
    if (i < N2) w2bf[i] = f ? ((const unsigned short*)w2src)[i] : f2bf(((const float*)w2src)[i]);
    else { long j = i - N2; w1bf[j] = f ? ((const unsigned short*)w1src)[j] : f2bf(((const float*)w1src)[j]); }
  }
}

// ---------------- conv1 5x5 pad2, 1->32, relu ----------------
__global__ void k_conv1(const float* __restrict__ xf, const float* __restrict__ w,
                        const float* __restrict__ bias, float* __restrict__ h1) {
  int x = threadIdx.x;        // 0..127
  int y = blockIdx.x;         // 0..31
  int b = blockIdx.y;         // 0..63
  const float* xin = xf + (long)b*4096;
  float in[25];
  #pragma unroll
  for (int ky = 0; ky < 5; ky++) {
    int yy = y + ky - 2;
    #pragma unroll
    for (int kx = 0; kx < 5; kx++) {
      int xx = x + kx - 2;
      in[ky*5+kx] = (yy >= 0 && yy < 32 && xx >= 0 && xx < 128) ? xin[yy*128 + xx] : 0.f;
    }
  }
  for (int co = 0; co < 32; co++) {
    float acc = bias[co];
    #pragma unroll
    for (int t = 0; t < 25; t++) acc += in[t] * w[co*25 + t];
    h1[(((long)b*32 + co)*32 + y)*128 + x] = fmaxf(acc, 0.f);
  }
}

// ---------------- conv2 3x3 pad1, 32->32, relu ----------------
#define LD2 132
__global__ __launch_bounds__(256) void k_conv2(const float* __restrict__ h1, const float* __restrict__ w,
                                               const float* __restrict__ bias, float* __restrict__ h2) {
  __shared__ float s[32][3][LD2];
  int y = blockIdx.x, b = blockIdx.y;
  int tid = threadIdx.x;
  for (int i = tid; i < 32*3*LD2; i += 256) {
    int ci = i / (3*LD2);
    int r  = (i / LD2) % 3;
    int xx = i % LD2;
    int yy = y + r - 1, sx = xx - 1;
    float v = 0.f;
    if (yy >= 0 && yy < 32 && sx >= 0 && sx < 128) v = h1[(((long)b*32+ci)*32+yy)*128+sx];
    s[ci][r][xx] = v;
  }
  __syncthreads();
  int x = tid & 127;
  int half = __builtin_amdgcn_readfirstlane(tid >> 7);
  const float* wb = w + half*4608;          // [ci][co16][9] contiguous
  float acc[16];
  #pragma unroll
  for (int i = 0; i < 16; i++) acc[i] = bias[half*16 + i];
  #pragma unroll 2
  for (int ci = 0; ci < 32; ci++) {
    float xv[9];
    #pragma unroll
    for (int r = 0; r < 3; r++)
      #pragma unroll
      for (int k = 0; k < 3; k++) xv[r*3+k] = s[ci][r][x + k];
    #pragma unroll
    for (int co = 0; co < 16; co++) {
      const float* wr = wb + (ci*16 + co)*9;
      #pragma unroll
      for (int t = 0; t < 9; t++) acc[co] += xv[t] * wr[t];
    }
  }
  #pragma unroll
  for (int co = 0; co < 16; co++)
    h2[(((long)b*32 + half*16 + co)*32 + y)*128 + x] = fmaxf(acc[co], 0.f);
}

// ---------------- maxpool 2x2 + channel mean ----------------
__global__ void k_pool(const float* __restrict__ h2, float* __restrict__ pooled, float* __restrict__ attm) {
  int bc = blockIdx.x;                 // b*32+c
  const float* src = h2 + (long)bc*4096;
  float* dst = pooled + (long)bc*1024;
  float sum = 0.f;
  for (int i = threadIdx.x; i < 1024; i += 256) {
    int py = i >> 6, px = i & 63;
    const float* p = src + py*256 + px*2;
    float m = fmaxf(fmaxf(p[0], p[1]), fmaxf(p[128], p[129]));
    dst[i] = m;
    sum += m;
  }
  __shared__ float red[256];
  red[threadIdx.x] = sum;
  __syncthreads();
  for (int s2 = 128; s2 > 0; s2 >>= 1) {
    if (threadIdx.x < s2) red[threadIdx.x] += red[threadIdx.x + s2];
    __syncthreads();
  }
  if (threadIdx.x == 0) attm[bc] = red[0] * (1.f/1024.f);
}

// ---------------- attention MLP ----------------
__global__ void k_att(const float* __restrict__ attm, const float* __restrict__ w1, const float* __restrict__ b1,
                      const float* __restrict__ w2, const float* __restrict__ b2, float* __restrict__ atts) {
  int b = threadIdx.x;
  if (b < 64) {
    float hb[4];
    #pragma unroll
    for (int j = 0; j < 4; j++) {
      float s = b1[j];
      for (int i = 0; i < 32; i++) s += attm[b*32+i]*w1[j*32+i];
      hb[j] = fmaxf(s, 0.f);
    }
    for (int o = 0; o < 32; o++) {
      float s = b2[o];
      #pragma unroll
      for (int j = 0; j < 4; j++) s += hb[j]*w2[o*4+j];
      atts[b*32+o] = 1.f/(1.f + __expf(-s));
    }
  }
}

// ---------------- scale + transpose to seq[b][t][f], f=c*16+hh ----------------
__global__ void k_seq(const float* __restrict__ pooled, const float* __restrict__ atts, float* __restrict__ seq) {
  for (int idx = blockIdx.x*256 + threadIdx.x; idx < 64*64*512; idx += gridDim.x*256) {
    int b = idx >> 15;
    int t = (idx >> 9) & 63;
    int fch = idx & 511;
    int c = fch >> 4, hh = fch & 15;
    seq[idx] = pooled[(((long)b*32 + c)*16 + hh)*64 + t] * atts[b*32 + c];
  }
}

// ---------------- natural cubic spline coeffs (Thomas, per (b,f)) ----------------
__global__ __launch_bounds__(256, 1) void k_spline(const float* __restrict__ seq, float* __restrict__ sb,
                                                   float* __restrict__ sc, float* __restrict__ sd) {
  int id = blockIdx.x*256 + threadIdx.x;     // 0..32767
  int b = id >> 9, f = id & 511;
  const float* xp = seq + (long)b*32768 + f;
  float xv[64];
  #pragma unroll
  for (int t = 0; t < 64; t++) xv[t] = xp[t*512];
  float cp[62], dp[62];
  float pc = 0.f, pd = 0.f;
  #pragma unroll
  for (int i = 0; i < 62; i++) {
    float rhs = 6.f*(xv[i+2] - 2.f*xv[i+1] + xv[i]);
    float inv = 1.f/(4.f - pc);
    pc = inv;
    pd = (rhs - pd)*inv;
    cp[i] = pc; dp[i] = pd;
  }
  #pragma unroll
  for (int i = 60; i >= 0; i--) dp[i] = dp[i] - cp[i]*dp[i+1];
  const float i6 = 1.f/6.f;
  #pragma unroll
  for (int t = 0; t < 63; t++) {
    float M0 = (t == 0)  ? 0.f : dp[t-1];
    float M1 = (t == 62) ? 0.f : dp[t];
    long o = ((long)b*63 + t)*512 + f;
    sb[o] = (xv[t+1] - xv[t]) - (2.f*M0 + M1)*i6;
    sc[o] = 0.5f*M0;
    sd[o] = (M1 - M0)*i6;
  }
}

// ---------------- dXdt table: all 253 quarter-steps ----------------
__global__ void k_dxt(const float* __restrict__ sb, const float* __restrict__ sc,
                      const float* __restrict__ sd, float* __restrict__ dxt) {
  for (long i = (long)blockIdx.x*256 + threadIdx.x; i < (long)253*32768; i += (long)gridDim.x*256) {
    int m = (int)(i >> 15);
    int bf = (int)(i & 32767);
    int b = bf >> 9, c = bf & 511;
    int seg = m >> 2; if (seg > 62) seg = 62;
    float fr = 0.25f*(float)m - (float)seg;
    long o = ((long)b*63 + seg)*512 + c;
    dxt[i] = sb[o] + 2.f*fr*sc[o] + (3.f*fr*fr)*sd[o];
  }
}

// ---------------- z0 = seq[:,0,:] @ initial_w^T + b ----------------
__global__ void k_z0(const float* __restrict__ seq, const float* __restrict__ iwT,
                     const float* __restrict__ ib, float* __restrict__ z0) {
  __shared__ float s0[512];
  int b = blockIdx.x, h = threadIdx.x;
  for (int c = h; c < 512; c += 64) s0[c] = seq[(long)b*32768 + c];
  __syncthreads();
  float acc = ib[h];
  for (int c = 0; c < 512; c++) acc += s0[c]*iwT[c*64 + h];
  z0[b*64 + h] = acc;
}

// ---------------- persistent RK4 CDE integrator ----------------
// v5.2: identical to round 10 EXCEPT the producer's data->flag ordering is
// now ARCHITECTURALLY enforced: the relaxed flag store carries no data
// dependency on the k store, and a workgroup-scope __syncthreads does NOT
// forbid hoisting an agent-scope relaxed store above it — codegen-dependent
// reordering lets consumers see the flag before k reaches the LLC and read
// poison (dropped-k => the deterministic-looking ~5-ulp error of rounds
// 9/10; rounds 2-7 were safe by codegen luck + acquire fences). Fix:
// s_waitcnt vmcnt(0) (LLVM's agent-release lowering — pure drain, no
// buffer_wbl2) + sched_barrier(0) (blocks compiler motion) between the k
// store and the flag store.
__global__ __launch_bounds__(512, 2) void k_ode(
    const float* __restrict__ z0buf,
    const unsigned short* __restrict__ w2bf,   // [32768][128]
    const unsigned short* __restrict__ w1bf,   // [128][64]
    const float* __restrict__ f1bias,
    const float* __restrict__ f2bias,
    const float* __restrict__ dxt,             // [253][64][512]
    const float* __restrict__ outw,
    const float* __restrict__ outb,
    uint32_t* kpart,                           // [504][4 bq][64 hb][16 b]
    uint32_t* flags,                           // [4 bq][64 cons][64 prod] u32 (poisoned)
    void* dout,
    const int* __restrict__ flag)
{
  __shared__ __align__(16) unsigned short zs[16*72];       // z bf16 [16 b][64 h] pad
  __shared__ __align__(16) unsigned short ub[16*136];      // u bf16 [16 b][128 u] pad
  __shared__ __align__(16) float dxs[16*524 + 10560];      // dx fp32 + CU-exclusivity pad
  __shared__ float kred[128];

  int tid = threadIdx.x;
  int bl  = blockIdx.x;
  int hb  = bl >> 2;            // 0..63 — this block's h (all 512 c)
  int bq  = bl & 3;             // b-quarter
  int B0  = bq*16;
  int lane = tid & 63, wv = tid >> 6;   // 8 waves
  int q = lane >> 4, ln = lane & 15;

  // ---- persistent fragments: wave wv owns c-rows wv*64..+64 ----
  v8bf w2f[4][4];
  #pragma unroll
  for (int jt = 0; jt < 4; jt++)
    #pragma unroll
    for (int ks = 0; ks < 4; ks++) {
      long row = (long)hb*512 + wv*64 + jt*16 + ln;
      w2f[jt][ks] = *(const v8bf*)(w2bf + row*128 + ks*32 + q*8);
    }
  v8bf w1f[2];                  // u-rows wv*16..+16
  #pragma unroll
  for (int ks = 0; ks < 2; ks++)
    w1f[ks] = *(const v8bf*)(w1bf + (wv*16 + ln)*64 + ks*32 + q*8);
  float fb2[4][4];
  #pragma unroll
  for (int jt = 0; jt < 4; jt++)
    #pragma unroll
    for (int r = 0; r < 4; r++)
      fb2[jt][r] = f2bias[(long)hb*512 + wv*64 + jt*16 + q*4 + r];
  float fb1[4];
  #pragma unroll
  for (int r = 0; r < 4; r++)
    fb1[r] = f1bias[wv*16 + q*4 + r];

  // z state: thread owns b-local = tid&15, h-pair = (tid>>4)*2
  int zbL = tid & 15;
  int hg  = tid >> 4;           // 0..31
  int h0  = hg*2;               // 0..62
  float z[2], zacc[2];
  #pragma unroll
  for (int i = 0; i < 2; i++) { z[i] = z0buf[(B0+zbL)*64 + h0 + i]; zacc[i] = 0.f; }

  const float dt6 = 0.5f/6.f;
  int e = 0;
  for (int step = 0; step < NSTEP; step++) {
    #pragma unroll 1
    for (int stage = 0; stage < 4; stage++, e++) {
      bool do_dx = (stage == 1) || (stage == 3) || (e == 0);
      int m = 2*step + ((stage + 1) >> 1);
      float4 dxr[4];
      if (do_dx) {
        #pragma unroll
        for (int i = 0; i < 4; i++) {
          int fi = i*512 + tid;          // 2048 float4 = [16 b][128 f4]
          int bb = fi >> 7, c4 = fi & 127;
          dxr[i] = *(const float4*)(dxt + (long)m*32768 + (B0+bb)*512 + c4*4);
        }
      }
      if (e > 0) {
        // wave-1 polls own 64-word flag region (producers of this cohort)
        if (tid >= 64 && tid < 128) {
          const uint32_t* fp = flags + ((long)bq*64 + hb)*64 + (tid - 64);
          while ((int)__hip_atomic_load(fp, __ATOMIC_RELAXED, __HIP_MEMORY_SCOPE_AGENT) < e)
            __builtin_amdgcn_s_sleep(1);
        }
        __syncthreads();
        // one-shot kv read: 2 words/thread, coalesced 64B per 16-thread group
        const uint32_t* kp = kpart + ((long)(e-1)*4 + bq)*1024;
        float kv[2];
        #pragma unroll
        for (int i = 0; i < 2; i++)
          kv[i] = __uint_as_float(__hip_atomic_load(kp + (h0+i)*16 + zbL,
                                   __ATOMIC_RELAXED, __HIP_MEMORY_SCOPE_AGENT));
        if (stage == 0) {
          uint32_t pk = 0;
          #pragma unroll
          for (int i = 0; i < 2; i++) {
            z[i] += dt6*(zacc[i] + kv[i]);
            zacc[i] = 0.f;
            pk |= ((uint32_t)f2bf(z[i])) << (16*i);
          }
          *(uint32_t*)(zs + zbL*72 + h0) = pk;
        } else {
          float wk = (stage == 1) ? 1.f : 2.f;
          float aa = (stage == 3) ? 0.5f : 0.25f;
          uint32_t pk = 0;
          #pragma unroll
          for (int i = 0; i < 2; i++) {
            zacc[i] += wk*kv[i];
            pk |= ((uint32_t)f2bf(z[i] + aa*kv[i])) << (16*i);
          }
          *(uint32_t*)(zs + zbL*72 + h0) = pk;
        }
      } else {
        uint32_t pk = ((uint32_t)f2bf(z[0])) | (((uint32_t)f2bf(z[1])) << 16);
        *(uint32_t*)(zs + zbL*72 + h0) = pk;
      }
      if (do_dx) {
        #pragma unroll
        for (int i = 0; i < 4; i++) {
          int fi = i*512 + tid;
          int bb = fi >> 7, c4 = fi & 127;
          *(float4*)(dxs + bb*524 + c4*4) = dxr[i];
        }
      }
      __syncthreads();
      // W1: wave computes u rows wv*16..+16 for the 16 b
      v8bf zf[2];
      #pragma unroll
      for (int ks = 0; ks < 2; ks++)
        zf[ks] = *(const v8bf*)(zs + ln*72 + ks*32 + q*8);
      {
        v4f ua = (v4f){0.f, 0.f, 0.f, 0.f};
        #pragma unroll
        for (int ks = 0; ks < 2; ks++)
          ua = __builtin_amdgcn_mfma_f32_16x16x32_bf16(w1f[ks], zf[ks], ua, 0, 0, 0);
        ushort4 pk;
        pk.x = f2bf(fmaxf(ua[0] + fb1[0], 0.f));
        pk.y = f2bf(fmaxf(ua[1] + fb1[1], 0.f));
        pk.z = f2bf(fmaxf(ua[2] + fb1[2], 0.f));
        pk.w = f2bf(fmaxf(ua[3] + fb1[3], 0.f));
        *(ushort4*)(ub + ln*136 + wv*16 + q*4) = pk;
      }
      __syncthreads();
      // W2 (wave's 64 c-rows, all 16 b) + tanh + dot dx -> per-wave partial
      v8bf uf[4];
      #pragma unroll
      for (int ks = 0; ks < 4; ks++)
        uf[ks] = *(const v8bf*)(ub + ln*136 + ks*32 + q*8);
      float ksum = 0.f;
      #pragma unroll
      for (int jt = 0; jt < 4; jt++) {
        v4f acc = (v4f){0.f, 0.f, 0.f, 0.f};
        #pragma unroll
        for (int ks = 0; ks < 4; ks++)
          acc = __builtin_amdgcn_mfma_f32_16x16x32_bf16(w2f[jt][ks], uf[ks], acc, 0, 0, 0);
        v4f dx4 = *(const v4f*)(dxs + ln*524 + wv*64 + jt*16 + q*4);
        #pragma unroll
        for (int r = 0; r < 4; r++) {
          float xv2 = acc[r] + fb2[jt][r];
          float ex = __expf(2.f*xv2);
          float th = 1.f - 2.f*__builtin_amdgcn_rcpf(ex + 1.f);
          ksum += th*dx4[r];
        }
      }
      ksum += __shfl_xor(ksum, 16, 64);
      ksum += __shfl_xor(ksum, 32, 64);
      if (lane < 16)
        kred[wv*16 + ln] = ksum;
      __syncthreads();
      // wave0: combine 8 wave-partials -> FINAL k, one 64B line store
      if (tid < 16) {
        float v = 0.f;
        #pragma unroll
        for (int w = 0; w < 8; w++) v += kred[w*16 + tid];
        __hip_atomic_store(kpart + (((long)e*4 + bq)*64 + hb)*16 + tid,
                           __float_as_uint(v),
                           __ATOMIC_RELAXED, __HIP_MEMORY_SCOPE_AGENT);
      }
      __syncthreads();
      // enforce k-data -> flag order: drain this wave's stores to the
      // coherence point (agent-release lowering) and pin compiler order.
      __builtin_amdgcn_s_waitcnt(0x0F70);   // vmcnt(0), expcnt/lgkmcnt free
      __builtin_amdgcn_sched_barrier(0);
      if (tid < 64)
        __hip_atomic_store(flags + ((long)bq*64 + tid)*64 + hb, (uint32_t)(e + 1),
                           __ATOMIC_RELAXED, __HIP_MEMORY_SCOPE_AGENT);
    }
  }
  // final: only output blocks (hb==0 -> bl<4) need the last k
  if (hb == 0) {
    if (tid >= 64 && tid < 128) {
      const uint32_t* fp = flags + ((long)bq*64 + 0)*64 + (tid - 64);
      while ((int)__hip_atomic_load(fp, __ATOMIC_RELAXED, __HIP_MEMORY_SCOPE_AGENT) < NEVAL)
        __builtin_amdgcn_s_sleep(1);
    }
    __syncthreads();
    {
      const uint32_t* kp = kpart + ((long)(NEVAL-1)*4 + bq)*1024;
      #pragma unroll
      for (int i = 0; i < 2; i++) {
        float kv = __uint_as_float(__hip_atomic_load(kp + (h0+i)*16 + zbL,
                                    __ATOMIC_RELAXED, __HIP_MEMORY_SCOPE_AGENT));
        z[i] += dt6*(zacc[i] + kv);
      }
    }
    float o0 = z[0]*outw[h0] + z[1]*outw[h0+1];
    float o1 = z[0]*outw[64+h0] + z[1]*outw[64+h0+1];
    __syncthreads();
    dxs[hg*32 + zbL*2 + 0] = o0;    // po[32 grp][16 b][2]
    dxs[hg*32 + zbL*2 + 1] = o1;
    __syncthreads();
    if (tid < 32) {
      int bloc = tid >> 1, comp = tid & 1;
      float s = outb[comp];
      #pragma unroll
      for (int g = 0; g < 32; g++) s += dxs[g*32 + bloc*2 + comp];
      int b = B0 + bloc;
      if (*flag) ((unsigned short*)dout)[b*2 + comp] = f2bf(s);
      else       ((float*)dout)[b*2 + comp] = s;
    }
  }
}

// ---------------- host ----------------
extern "C" void kernel_launch(void* const* d_in, const int* in_sizes, int n_in,
                              void* d_out, int out_size, void* d_ws, size_t ws_size,
                              hipStream_t stream) {
  (void)in_sizes; (void)n_in; (void)out_size; (void)ws_size;
  float* ws = (float*)d_ws;
  size_t o = 0;
  auto alloc = [&](size_t n) { size_t r = o; o += (n + 63) & ~(size_t)63; return r; };
  size_t o_flag = alloc(64);
  size_t o_xf   = alloc(262144);
  size_t o_c1w  = alloc(800);
  size_t o_c1b  = alloc(32);
  size_t o_c2w  = alloc(9216);
  size_t o_c2b  = alloc(32);
  size_t o_a1w  = alloc(128);
  size_t o_a1b  = alloc(4);
  size_t o_a2w  = alloc(128);
  size_t o_a2b  = alloc(32);
  size_t o_iwT  = alloc(32768);
  size_t o_ib   = alloc(64);
  size_t o_f1b  = alloc(128);
  size_t o_f2b  = alloc(32768);
  size_t o_ow   = alloc(128);
  size_t o_ob   = alloc(2);
  size_t o_z0   = alloc(4096);
  size_t o_attm = alloc(2048);
  size_t o_atts = alloc(2048);
  size_t o_w1bf = alloc(4096);      // ushort[8192]
  size_t o_w2bf = alloc(2097152);   // ushort[4194304]
  size_t o_h1   = alloc(8388608);   // conv1 out; later pooled+seq; later dxt
  size_t o_h2   = alloc(8388608);   // conv2 out; later sb/sc/sd
  size_t o_kpart= alloc(4128768);   // k data [504][4][64][16] + flags tail (fresh, poisoned)
  size_t o_pool = o_h1;
  size_t o_seq  = o_h1 + 2097152;
  size_t o_dxt  = o_h1;
  size_t o_sb   = o_h2;
  size_t o_sc   = o_h2 + 2064384;
  size_t o_sd   = o_h2 + 4128768;
  size_t o_flags= o_kpart + 2064384;  // [4][64][64] u32 — fresh poisoned memory

  int* flag = (int*)(ws + o_flag);

  hipLaunchKernelGGL(k_detect, dim3(1), dim3(256), 0, stream, (const uint32_t*)d_in[0], flag);

  CvtArgs ca;
  const int  si[NCVT]  = {0,1,2,3,4,5,6,7,8,9,10,12,14,15,16};
  const size_t dofs[NCVT] = {o_xf,o_c1w,o_c1b,o_c2w,o_c2b,o_a1w,o_a1b,o_a2w,o_a2b,o_iwT,o_ib,o_f1b,o_f2b,o_ow,o_ob};
  const int  ln[NCVT]  = {262144,800,32,9216,32,128,4,128,32,32768,64,128,32768,128,2};
  int tot = 0;
  for (int i = 0; i < NCVT; i++) {
    ca.src[i] = d_in[si[i]];
    ca.dstoff[i] = (int)dofs[i];
    ca.len[i] = ln[i];
    ca.kind[i] = (si[i] == 9) ? 1 : ((si[i] == 3) ? 2 : 0);
    tot += ln[i];
  }
  ca.total = tot;
  hipLaunchKernelGGL(k_convert, dim3(512), dim3(256), 0, stream, ca, ws, flag);
  hipLaunchKernelGGL(k_wbf16, dim3(2048), dim3(256), 0, stream, d_in[13], d_in[11],
                     (unsigned short*)(ws + o_w2bf), (unsigned short*)(ws + o_w1bf), flag);
  hipLaunchKernelGGL(k_conv1, dim3(32,64), dim3(128), 0, stream, ws+o_xf, ws+o_c1w, ws+o_c1b, ws+o_h1);
  hipLaunchKernelGGL(k_conv2, dim3(32,64), dim3(256), 0, stream, ws+o_h1, ws+o_c2w, ws+o_c2b, ws+o_h2);
  hipLaunchKernelGGL(k_pool, dim3(2048), dim3(256), 0, stream, ws+o_h2, ws+o_pool, ws+o_attm);
  hipLaunchKernelGGL(k_att, dim3(1), dim3(64), 0, stream, ws+o_attm, ws+o_a1w, ws+o_a1b, ws+o_a2w, ws+o_a2b, ws+o_atts);
  hipLaunchKernelGGL(k_seq, dim3(2048), dim3(256), 0, stream, ws+o_pool, ws+o_atts, ws+o_seq);
  hipLaunchKernelGGL(k_spline, dim3(128), dim3(256), 0, stream, ws+o_seq, ws+o_sb, ws+o_sc, ws+o_sd);
  hipLaunchKernelGGL(k_z0, dim3(64), dim3(64), 0, stream, ws+o_seq, ws+o_iwT, ws+o_ib, ws+o_z0);
  hipLaunchKernelGGL(k_dxt, dim3(4096), dim3(256), 0, stream, ws+o_sb, ws+o_sc, ws+o_sd, ws+o_dxt);

  hipLaunchKernelGGL(k_ode, dim3(256), dim3(512), 0, stream,
                     ws + o_z0,
                     (const unsigned short*)(ws + o_w2bf),
                     (const unsigned short*)(ws + o_w1bf),
                     ws + o_f1b, ws + o_f2b,
                     ws + o_dxt, ws + o_ow, ws + o_ob,
                     (uint32_t*)(ws + o_kpart), (uint32_t*)(ws + o_flags),
                     d_out, (const int*)flag);
}

// Round 12
// 1631.118 us; speedup vs baseline: 1.2138x; 1.2138x over previous
//
#include <hip/hip_runtime.h>
#include <hip/hip_bf16.h>
#include <stdint.h>

#define NSTEP 126
#define NEVAL 504
#define POISON 0xAAAAAAAAu

typedef __bf16 v8bf __attribute__((ext_vector_type(8)));
typedef float  v4f  __attribute__((ext_vector_type(4)));

__device__ __forceinline__ unsigned short f2bf(float x) {
  union { float f; uint32_t u; } v; v.f = x;
  uint32_t u = v.u;
  uint32_t r = (u + 0x7FFFu + ((u >> 16) & 1u)) >> 16;
  return (unsigned short)r;
}
__device__ __forceinline__ float bf2f(unsigned short b) {
  union { uint32_t u; float f; } v; v.u = ((uint32_t)b) << 16;
  return v.f;
}

// ---------------- dtype detection ----------------
__global__ void k_detect(const uint32_t* __restrict__ xw, int* flag) {
  __shared__ int cnt;
  if (threadIdx.x == 0) cnt = 0;
  __syncthreads();
  uint32_t w = xw[threadIdx.x];
  int e = (int)((w >> 7) & 0xFF);
  int good = ((e >= 100) && (e <= 144)) || ((w & 0xFFFFu) == 0u);
  atomicAdd(&cnt, good);
  __syncthreads();
  if (threadIdx.x == 0) *flag = (cnt >= 192) ? 1 : 0;
}

// ---------------- input conversion ----------------
#define NCVT 15
struct CvtArgs {
  const void* src[NCVT];
  int dstoff[NCVT];
  int len[NCVT];
  int kind[NCVT];   // 1 = transpose initial_w; 2 = conv2 weight relayout
  int total;
};
__global__ void k_convert(CvtArgs a, float* __restrict__ ws, const int* __restrict__ flag) {
  int f = *flag;
  for (int i = blockIdx.x*256 + threadIdx.x; i < a.total; i += gridDim.x*256) {
    int t = 0; int rem = i;
    while (rem >= a.len[t]) { rem -= a.len[t]; t++; }
    float v = f ? bf2f(((const unsigned short*)a.src[t])[rem])
                : ((const float*)a.src[t])[rem];
    int d;
    if (a.kind[t] == 1) { int h = rem >> 9, c = rem & 511; d = a.dstoff[t] + c*64 + h; }
    else if (a.kind[t] == 2) {
      int co = rem / 288, r2 = rem % 288;
      int ci = r2 / 9, tt = r2 % 9;
      d = a.dstoff[t] + (co >> 4)*4608 + (ci*16 + (co & 15))*9 + tt;
    }
    else d = a.dstoff[t] + rem;
    ws[d] = v;
  }
}

__global__ void k_wbf16(const void* __restrict__ w2src, const void* __restrict__ w1src,
                        unsigned short* __restrict__ w2bf, unsigned short* __restrict__ w1bf,
                        const int* __restrict__ flag) {
  int f = *flag;
  const long N2 = 4194304, N1 = 8192;
  for (long i = (long)blockIdx.x*256 + threadIdx.x; i < N2 + N1; i += (long)gridDim.x*256) {
    if (i < N2) w2bf[i] = f ? ((const unsigned short*)w2src)[i] : f2bf(((const float*)w2src)[i]);
    else { long j = i - N2; w1bf[j] = f ? ((const unsigned short*)w1src)[j] : f2bf(((const float*)w1src)[j]); }
  }
}

// ---------------- conv1 5x5 pad2, 1->32, relu ----------------
__global__ void k_conv1(const float* __restrict__ xf, const float* __restrict__ w,
                        const float* __restrict__ bias, float* __restrict__ h1) {
  int x = threadIdx.x;        // 0..127
  int y = blockIdx.x;         // 0..31
  int b = blockIdx.y;         // 0..63
  const float* xin = xf + (long)b*4096;
  float in[25];
  #pragma unroll
  for (int ky = 0; ky < 5; ky++) {
    int yy = y + ky - 2;
    #pragma unroll
    for (int kx = 0; kx < 5; kx++) {
      int xx = x + kx - 2;
      in[ky*5+kx] = (yy >= 0 && yy < 32 && xx >= 0 && xx < 128) ? xin[yy*128 + xx] : 0.f;
    }
  }
  for (int co = 0; co < 32; co++) {
    float acc = bias[co];
    #pragma unroll
    for (int t = 0; t < 25; t++) acc += in[t] * w[co*25 + t];
    h1[(((long)b*32 + co)*32 + y)*128 + x] = fmaxf(acc, 0.f);
  }
}

// ---------------- conv2 3x3 pad1, 32->32, relu ----------------
#define LD2 132
__global__ __launch_bounds__(256) void k_conv2(const float* __restrict__ h1, const float* __restrict__ w,
                                               const float* __restrict__ bias, float* __restrict__ h2) {
  __shared__ float s[32][3][LD2];
  int y = blockIdx.x, b = blockIdx.y;
  int tid = threadIdx.x;
  for (int i = tid; i < 32*3*LD2; i += 256) {
    int ci = i / (3*LD2);
    int r  = (i / LD2) % 3;
    int xx = i % LD2;
    int yy = y + r - 1, sx = xx - 1;
    float v = 0.f;
    if (yy >= 0 && yy < 32 && sx >= 0 && sx < 128) v = h1[(((long)b*32+ci)*32+yy)*128+sx];
    s[ci][r][xx] = v;
  }
  __syncthreads();
  int x = tid & 127;
  int half = __builtin_amdgcn_readfirstlane(tid >> 7);
  const float* wb = w + half*4608;          // [ci][co16][9] contiguous
  float acc[16];
  #pragma unroll
  for (int i = 0; i < 16; i++) acc[i] = bias[half*16 + i];
  #pragma unroll 2
  for (int ci = 0; ci < 32; ci++) {
    float xv[9];
    #pragma unroll
    for (int r = 0; r < 3; r++)
      #pragma unroll
      for (int k = 0; k < 3; k++) xv[r*3+k] = s[ci][r][x + k];
    #pragma unroll
    for (int co = 0; co < 16; co++) {
      const float* wr = wb + (ci*16 + co)*9;
      #pragma unroll
      for (int t = 0; t < 9; t++) acc[co] += xv[t] * wr[t];
    }
  }
  #pragma unroll
  for (int co = 0; co < 16; co++)
    h2[(((long)b*32 + half*16 + co)*32 + y)*128 + x] = fmaxf(acc[co], 0.f);
}

// ---------------- maxpool 2x2 + channel mean ----------------
__global__ void k_pool(const float* __restrict__ h2, float* __restrict__ pooled, float* __restrict__ attm) {
  int bc = blockIdx.x;                 // b*32+c
  const float* src = h2 + (long)bc*4096;
  float* dst = pooled + (long)bc*1024;
  float sum = 0.f;
  for (int i = threadIdx.x; i < 1024; i += 256) {
    int py = i >> 6, px = i & 63;
    const float* p = src + py*256 + px*2;
    float m = fmaxf(fmaxf(p[0], p[1]), fmaxf(p[128], p[129]));
    dst[i] = m;
    sum += m;
  }
  __shared__ float red[256];
  red[threadIdx.x] = sum;
  __syncthreads();
  for (int s2 = 128; s2 > 0; s2 >>= 1) {
    if (threadIdx.x < s2) red[threadIdx.x] += red[threadIdx.x + s2];
    __syncthreads();
  }
  if (threadIdx.x == 0) attm[bc] = red[0] * (1.f/1024.f);
}

// ---------------- attention MLP ----------------
__global__ void k_att(const float* __restrict__ attm, const float* __restrict__ w1, const float* __restrict__ b1,
                      const float* __restrict__ w2, const float* __restrict__ b2, float* __restrict__ atts) {
  int b = threadIdx.x;
  if (b < 64) {
    float hb[4];
    #pragma unroll
    for (int j = 0; j < 4; j++) {
      float s = b1[j];
      for (int i = 0; i < 32; i++) s += attm[b*32+i]*w1[j*32+i];
      hb[j] = fmaxf(s, 0.f);
    }
    for (int o = 0; o < 32; o++) {
      float s = b2[o];
      #pragma unroll
      for (int j = 0; j < 4; j++) s += hb[j]*w2[o*4+j];
      atts[b*32+o] = 1.f/(1.f + __expf(-s));
    }
  }
}

// ---------------- scale + transpose to seq[b][t][f], f=c*16+hh ----------------
__global__ void k_seq(const float* __restrict__ pooled, const float* __restrict__ atts, float* __restrict__ seq) {
  for (int idx = blockIdx.x*256 + threadIdx.x; idx < 64*64*512; idx += gridDim.x*256) {
    int b = idx >> 15;
    int t = (idx >> 9) & 63;
    int fch = idx & 511;
    int c = fch >> 4, hh = fch & 15;
    seq[idx] = pooled[(((long)b*32 + c)*16 + hh)*64 + t] * atts[b*32 + c];
  }
}

// ---------------- natural cubic spline coeffs (Thomas, per (b,f)) ----------------
__global__ __launch_bounds__(256, 1) void k_spline(const float* __restrict__ seq, float* __restrict__ sb,
                                                   float* __restrict__ sc, float* __restrict__ sd) {
  int id = blockIdx.x*256 + threadIdx.x;     // 0..32767
  int b = id >> 9, f = id & 511;
  const float* xp = seq + (long)b*32768 + f;
  float xv[64];
  #pragma unroll
  for (int t = 0; t < 64; t++) xv[t] = xp[t*512];
  float cp[62], dp[62];
  float pc = 0.f, pd = 0.f;
  #pragma unroll
  for (int i = 0; i < 62; i++) {
    float rhs = 6.f*(xv[i+2] - 2.f*xv[i+1] + xv[i]);
    float inv = 1.f/(4.f - pc);
    pc = inv;
    pd = (rhs - pd)*inv;
    cp[i] = pc; dp[i] = pd;
  }
  #pragma unroll
  for (int i = 60; i >= 0; i--) dp[i] = dp[i] - cp[i]*dp[i+1];
  const float i6 = 1.f/6.f;
  #pragma unroll
  for (int t = 0; t < 63; t++) {
    float M0 = (t == 0)  ? 0.f : dp[t-1];
    float M1 = (t == 62) ? 0.f : dp[t];
    long o = ((long)b*63 + t)*512 + f;
    sb[o] = (xv[t+1] - xv[t]) - (2.f*M0 + M1)*i6;
    sc[o] = 0.5f*M0;
    sd[o] = (M1 - M0)*i6;
  }
}

// ---------------- dXdt table: all 253 quarter-steps ----------------
__global__ void k_dxt(const float* __restrict__ sb, const float* __restrict__ sc,
                      const float* __restrict__ sd, float* __restrict__ dxt) {
  for (long i = (long)blockIdx.x*256 + threadIdx.x; i < (long)253*32768; i += (long)gridDim.x*256) {
    int m = (int)(i >> 15);
    int bf = (int)(i & 32767);
    int b = bf >> 9, c = bf & 511;
    int seg = m >> 2; if (seg > 62) seg = 62;
    float fr = 0.25f*(float)m - (float)seg;
    long o = ((long)b*63 + seg)*512 + c;
    dxt[i] = sb[o] + 2.f*fr*sc[o] + (3.f*fr*fr)*sd[o];
  }
}

// ---------------- z0 = seq[:,0,:] @ initial_w^T + b ----------------
__global__ void k_z0(const float* __restrict__ seq, const float* __restrict__ iwT,
                     const float* __restrict__ ib, float* __restrict__ z0) {
  __shared__ float s0[512];
  int b = blockIdx.x, h = threadIdx.x;
  for (int c = h; c < 512; c += 64) s0[c] = seq[(long)b*32768 + c];
  __syncthreads();
  float acc = ib[h];
  for (int c = 0; c < 512; c++) acc += s0[c]*iwT[c*64 + h];
  z0[b*64 + h] = acc;
}

// ---------------- persistent RK4 CDE integrator ----------------
// v6: data-is-the-flag. Each (bq,hb) k-slice is ONE 64B line written by a
// single coalesced 16-lane store; its arrival at the LLC is the signal
// (producer nudges an accidental 0xAAAAAAAA value by 1 ulp). Consumer
// wave-1 polls one word per line (64 lanes -> 64 lines, fan-in 64/line,
// same as v5's flags); since single-line store visibility-atomicity is
// unverified, each thread's kv read keeps a poison-fallback reload loop
// (zero steady-state cost). Deletes the vmcnt(0) drain, sched_barrier,
// flag store, and the trailing barrier (WAR on kred/zs/dxs/ub is covered
// by the next eval's poll barrier — audited). Numerics identical to v5.2
// (absmax 2.4414e-4 = 1 ulp).
__global__ __launch_bounds__(512, 2) void k_ode(
    const float* __restrict__ z0buf,
    const unsigned short* __restrict__ w2bf,   // [32768][128]
    const unsigned short* __restrict__ w1bf,   // [128][64]
    const float* __restrict__ f1bias,
    const float* __restrict__ f2bias,
    const float* __restrict__ dxt,             // [253][64][512]
    const float* __restrict__ outw,
    const float* __restrict__ outb,
    uint32_t* kpart,                           // [504][4 bq][64 hb][16 b] (poisoned)
    void* dout,
    const int* __restrict__ flag)
{
  __shared__ __align__(16) unsigned short zs[16*72];       // z bf16 [16 b][64 h] pad
  __shared__ __align__(16) unsigned short ub[16*136];      // u bf16 [16 b][128 u] pad
  __shared__ __align__(16) float dxs[16*524 + 10560];      // dx fp32 + CU-exclusivity pad
  __shared__ float kred[128];

  int tid = threadIdx.x;
  int bl  = blockIdx.x;
  int hb  = bl >> 2;            // 0..63 — this block's h (all 512 c)
  int bq  = bl & 3;             // b-quarter
  int B0  = bq*16;
  int lane = tid & 63, wv = tid >> 6;   // 8 waves
  int q = lane >> 4, ln = lane & 15;

  // ---- persistent fragments: wave wv owns c-rows wv*64..+64 ----
  v8bf w2f[4][4];
  #pragma unroll
  for (int jt = 0; jt < 4; jt++)
    #pragma unroll
    for (int ks = 0; ks < 4; ks++) {
      long row = (long)hb*512 + wv*64 + jt*16 + ln;
      w2f[jt][ks] = *(const v8bf*)(w2bf + row*128 + ks*32 + q*8);
    }
  v8bf w1f[2];                  // u-rows wv*16..+16
  #pragma unroll
  for (int ks = 0; ks < 2; ks++)
    w1f[ks] = *(const v8bf*)(w1bf + (wv*16 + ln)*64 + ks*32 + q*8);
  float fb2[4][4];
  #pragma unroll
  for (int jt = 0; jt < 4; jt++)
    #pragma unroll
    for (int r = 0; r < 4; r++)
      fb2[jt][r] = f2bias[(long)hb*512 + wv*64 + jt*16 + q*4 + r];
  float fb1[4];
  #pragma unroll
  for (int r = 0; r < 4; r++)
    fb1[r] = f1bias[wv*16 + q*4 + r];

  // z state: thread owns b-local = tid&15, h-pair = (tid>>4)*2
  int zbL = tid & 15;
  int hg  = tid >> 4;           // 0..31
  int h0  = hg*2;               // 0..62
  float z[2], zacc[2];
  #pragma unroll
  for (int i = 0; i < 2; i++) { z[i] = z0buf[(B0+zbL)*64 + h0 + i]; zacc[i] = 0.f; }

  const float dt6 = 0.5f/6.f;
  int e = 0;
  for (int step = 0; step < NSTEP; step++) {
    #pragma unroll 1
    for (int stage = 0; stage < 4; stage++, e++) {
      bool do_dx = (stage == 1) || (stage == 3) || (e == 0);
      int m = 2*step + ((stage + 1) >> 1);
      float4 dxr[4];
      if (do_dx) {
        #pragma unroll
        for (int i = 0; i < 4; i++) {
          int fi = i*512 + tid;          // 2048 float4 = [16 b][128 f4]
          int bb = fi >> 7, c4 = fi & 127;
          dxr[i] = *(const float4*)(dxt + (long)m*32768 + (B0+bb)*512 + c4*4);
        }
      }
      if (e > 0) {
        const uint32_t* kp = kpart + ((long)(e-1)*4 + bq)*1024;
        // wave-1: poll one word per 64B k-line (line = one hb's 16 b values)
        if (tid >= 64 && tid < 128) {
          const uint32_t* pp = kp + (tid - 64)*16;
          while (__hip_atomic_load(pp, __ATOMIC_RELAXED, __HIP_MEMORY_SCOPE_AGENT) == POISON)
            __builtin_amdgcn_s_sleep(1);
        }
        __syncthreads();
        // kv read with poison-fallback (steady state: no spin)
        float kv[2];
        #pragma unroll
        for (int i = 0; i < 2; i++) {
          const uint32_t* p = kp + (h0+i)*16 + zbL;
          uint32_t v = __hip_atomic_load(p, __ATOMIC_RELAXED, __HIP_MEMORY_SCOPE_AGENT);
          while (v == POISON) {
            __builtin_amdgcn_s_sleep(1);
            v = __hip_atomic_load(p, __ATOMIC_RELAXED, __HIP_MEMORY_SCOPE_AGENT);
          }
          kv[i] = __uint_as_float(v);
        }
        if (stage == 0) {
          uint32_t pk = 0;
          #pragma unroll
          for (int i = 0; i < 2; i++) {
            z[i] += dt6*(zacc[i] + kv[i]);
            zacc[i] = 0.f;
            pk |= ((uint32_t)f2bf(z[i])) << (16*i);
          }
          *(uint32_t*)(zs + zbL*72 + h0) = pk;
        } else {
          float wk = (stage == 1) ? 1.f : 2.f;
          float aa = (stage == 3) ? 0.5f : 0.25f;
          uint32_t pk = 0;
          #pragma unroll
          for (int i = 0; i < 2; i++) {
            zacc[i] += wk*kv[i];
            pk |= ((uint32_t)f2bf(z[i] + aa*kv[i])) << (16*i);
          }
          *(uint32_t*)(zs + zbL*72 + h0) = pk;
        }
      } else {
        uint32_t pk = ((uint32_t)f2bf(z[0])) | (((uint32_t)f2bf(z[1])) << 16);
        *(uint32_t*)(zs + zbL*72 + h0) = pk;
      }
      if (do_dx) {
        #pragma unroll
        for (int i = 0; i < 4; i++) {
          int fi = i*512 + tid;
          int bb = fi >> 7, c4 = fi & 127;
          *(float4*)(dxs + bb*524 + c4*4) = dxr[i];
        }
      }
      __syncthreads();
      // W1: wave computes u rows wv*16..+16 for the 16 b
      v8bf zf[2];
      #pragma unroll
      for (int ks = 0; ks < 2; ks++)
        zf[ks] = *(const v8bf*)(zs + ln*72 + ks*32 + q*8);
      {
        v4f ua = (v4f){0.f, 0.f, 0.f, 0.f};
        #pragma unroll
        for (int ks = 0; ks < 2; ks++)
          ua = __builtin_amdgcn_mfma_f32_16x16x32_bf16(w1f[ks], zf[ks], ua, 0, 0, 0);
        ushort4 pk;
        pk.x = f2bf(fmaxf(ua[0] + fb1[0], 0.f));
        pk.y = f2bf(fmaxf(ua[1] + fb1[1], 0.f));
        pk.z = f2bf(fmaxf(ua[2] + fb1[2], 0.f));
        pk.w = f2bf(fmaxf(ua[3] + fb1[3], 0.f));
        *(ushort4*)(ub + ln*136 + wv*16 + q*4) = pk;
      }
      __syncthreads();
      // W2 (wave's 64 c-rows, all 16 b) + tanh + dot dx -> per-wave partial
      v8bf uf[4];
      #pragma unroll
      for (int ks = 0; ks < 4; ks++)
        uf[ks] = *(const v8bf*)(ub + ln*136 + ks*32 + q*8);
      float ksum = 0.f;
      #pragma unroll
      for (int jt = 0; jt < 4; jt++) {
        v4f acc = (v4f){0.f, 0.f, 0.f, 0.f};
        #pragma unroll
        for (int ks = 0; ks < 4; ks++)
          acc = __builtin_amdgcn_mfma_f32_16x16x32_bf16(w2f[jt][ks], uf[ks], acc, 0, 0, 0);
        v4f dx4 = *(const v4f*)(dxs + ln*524 + wv*64 + jt*16 + q*4);
        #pragma unroll
        for (int r = 0; r < 4; r++) {
          float xv2 = acc[r] + fb2[jt][r];
          float ex = __expf(2.f*xv2);
          float th = 1.f - 2.f*__builtin_amdgcn_rcpf(ex + 1.f);
          ksum += th*dx4[r];
        }
      }
      ksum += __shfl_xor(ksum, 16, 64);
      ksum += __shfl_xor(ksum, 32, 64);
      if (lane < 16)
        kred[wv*16 + ln] = ksum;
      __syncthreads();
      // wave0: combine 8 wave-partials -> FINAL k, one 64B line store.
      // The store itself is the readiness signal (nudge the poison collision).
      if (tid < 16) {
        float v = 0.f;
        #pragma unroll
        for (int w = 0; w < 8; w++) v += kred[w*16 + tid];
        uint32_t uv = __float_as_uint(v);
        if (uv == POISON) uv ^= 1u;
        __hip_atomic_store(kpart + (((long)e*4 + bq)*64 + hb)*16 + tid, uv,
                           __ATOMIC_RELAXED, __HIP_MEMORY_SCOPE_AGENT);
      }
      // no trailing barrier: next eval's poll barrier covers all WAR hazards
    }
  }
  // final: only output blocks (hb==0 -> bl<4) need the last k
  if (hb == 0) {
    const uint32_t* kp = kpart + ((long)(NEVAL-1)*4 + bq)*1024;
    if (tid >= 64 && tid < 128) {
      const uint32_t* pp = kp + (tid - 64)*16;
      while (__hip_atomic_load(pp, __ATOMIC_RELAXED, __HIP_MEMORY_SCOPE_AGENT) == POISON)
        __builtin_amdgcn_s_sleep(1);
    }
    __syncthreads();
    {
      #pragma unroll
      for (int i = 0; i < 2; i++) {
        const uint32_t* p = kp + (h0+i)*16 + zbL;
        uint32_t v = __hip_atomic_load(p, __ATOMIC_RELAXED, __HIP_MEMORY_SCOPE_AGENT);
        while (v == POISON) {
          __builtin_amdgcn_s_sleep(1);
          v = __hip_atomic_load(p, __ATOMIC_RELAXED, __HIP_MEMORY_SCOPE_AGENT);
        }
        z[i] += dt6*(zacc[i] + __uint_as_float(v));
      }
    }
    float o0 = z[0]*outw[h0] + z[1]*outw[h0+1];
    float o1 = z[0]*outw[64+h0] + z[1]*outw[64+h0+1];
    __syncthreads();
    dxs[hg*32 + zbL*2 + 0] = o0;    // po[32 grp][16 b][2]
    dxs[hg*32 + zbL*2 + 1] = o1;
    __syncthreads();
    if (tid < 32) {
      int bloc = tid >> 1, comp = tid & 1;
      float s = outb[comp];
      #pragma unroll
      for (int g = 0; g < 32; g++) s += dxs[g*32 + bloc*2 + comp];
      int b = B0 + bloc;
      if (*flag) ((unsigned short*)dout)[b*2 + comp] = f2bf(s);
      else       ((float*)dout)[b*2 + comp] = s;
    }
  }
}

// ---------------- host ----------------
extern "C" void kernel_launch(void* const* d_in, const int* in_sizes, int n_in,
                              void* d_out, int out_size, void* d_ws, size_t ws_size,
                              hipStream_t stream) {
  (void)in_sizes; (void)n_in; (void)out_size; (void)ws_size;
  float* ws = (float*)d_ws;
  size_t o = 0;
  auto alloc = [&](size_t n) { size_t r = o; o += (n + 63) & ~(size_t)63; return r; };
  size_t o_flag = alloc(64);
  size_t o_xf   = alloc(262144);
  size_t o_c1w  = alloc(800);
  size_t o_c1b  = alloc(32);
  size_t o_c2w  = alloc(9216);
  size_t o_c2b  = alloc(32);
  size_t o_a1w  = alloc(128);
  size_t o_a1b  = alloc(4);
  size_t o_a2w  = alloc(128);
  size_t o_a2b  = alloc(32);
  size_t o_iwT  = alloc(32768);
  size_t o_ib   = alloc(64);
  size_t o_f1b  = alloc(128);
  size_t o_f2b  = alloc(32768);
  size_t o_ow   = alloc(128);
  size_t o_ob   = alloc(2);
  size_t o_z0   = alloc(4096);
  size_t o_attm = alloc(2048);
  size_t o_atts = alloc(2048);
  size_t o_w1bf = alloc(4096);      // ushort[8192]
  size_t o_w2bf = alloc(2097152);   // ushort[4194304]
  size_t o_h1   = alloc(8388608);   // conv1 out; later pooled+seq; later dxt
  size_t o_h2   = alloc(8388608);   // conv2 out; later sb/sc/sd
  size_t o_kpart= alloc(4128768);   // k data [504][4][64][16] — fresh, harness-poisoned
  size_t o_pool = o_h1;
  size_t o_seq  = o_h1 + 2097152;
  size_t o_dxt  = o_h1;
  size_t o_sb   = o_h2;
  size_t o_sc   = o_h2 + 2064384;
  size_t o_sd   = o_h2 + 4128768;

  int* flag = (int*)(ws + o_flag);

  hipLaunchKernelGGL(k_detect, dim3(1), dim3(256), 0, stream, (const uint32_t*)d_in[0], flag);

  CvtArgs ca;
  const int  si[NCVT]  = {0,1,2,3,4,5,6,7,8,9,10,12,14,15,16};
  const size_t dofs[NCVT] = {o_xf,o_c1w,o_c1b,o_c2w,o_c2b,o_a1w,o_a1b,o_a2w,o_a2b,o_iwT,o_ib,o_f1b,o_f2b,o_ow,o_ob};
  const int  ln[NCVT]  = {262144,800,32,9216,32,128,4,128,32,32768,64,128,32768,128,2};
  int tot = 0;
  for (int i = 0; i < NCVT; i++) {
    ca.src[i] = d_in[si[i]];
    ca.dstoff[i] = (int)dofs[i];
    ca.len[i] = ln[i];
    ca.kind[i] = (si[i] == 9) ? 1 : ((si[i] == 3) ? 2 : 0);
    tot += ln[i];
  }
  ca.total = tot;
  hipLaunchKernelGGL(k_convert, dim3(512), dim3(256), 0, stream, ca, ws, flag);
  hipLaunchKernelGGL(k_wbf16, dim3(2048), dim3(256), 0, stream, d_in[13], d_in[11],
                     (unsigned short*)(ws + o_w2bf), (unsigned short*)(ws + o_w1bf), flag);
  hipLaunchKernelGGL(k_conv1, dim3(32,64), dim3(128), 0, stream, ws+o_xf, ws+o_c1w, ws+o_c1b, ws+o_h1);
  hipLaunchKernelGGL(k_conv2, dim3(32,64), dim3(256), 0, stream, ws+o_h1, ws+o_c2w, ws+o_c2b, ws+o_h2);
  hipLaunchKernelGGL(k_pool, dim3(2048), dim3(256), 0, stream, ws+o_h2, ws+o_pool, ws+o_attm);
  hipLaunchKernelGGL(k_att, dim3(1), dim3(64), 0, stream, ws+o_attm, ws+o_a1w, ws+o_a1b, ws+o_a2w, ws+o_a2b, ws+o_atts);
  hipLaunchKernelGGL(k_seq, dim3(2048), dim3(256), 0, stream, ws+o_pool, ws+o_atts, ws+o_seq);
  hipLaunchKernelGGL(k_spline, dim3(128), dim3(256), 0, stream, ws+o_seq, ws+o_sb, ws+o_sc, ws+o_sd);
  hipLaunchKernelGGL(k_z0, dim3(64), dim3(64), 0, stream, ws+o_seq, ws+o_iwT, ws+o_ib, ws+o_z0);
  hipLaunchKernelGGL(k_dxt, dim3(4096), dim3(256), 0, stream, ws+o_sb, ws+o_sc, ws+o_sd, ws+o_dxt);

  hipLaunchKernelGGL(k_ode, dim3(256), dim3(512), 0, stream,
                     ws + o_z0,
                     (const unsigned short*)(ws + o_w2bf),
                     (const unsigned short*)(ws + o_w1bf),
                     ws + o_f1b, ws + o_f2b,
                     ws + o_dxt, ws + o_ow, ws + o_ob,
                     (uint32_t*)(ws + o_kpart),
                     d_out, (const int*)flag);
}